// Round 13
// baseline (106.994 us; speedup 1.0000x reference)
//
#include <hip/hip_runtime.h>

// EPN layer: B=8, N=256, DH=32, DX=3, DQ=1, DE=8, H1=H2=32, DIN=80.
// layer1 = relu(Pa[i] + Pb'[j] + e_ij@W1e), Pb' has b1 folded in.
// b3 cancels in 0.5*(elec_ij - elec_ji).
//
// R1: remat. R3: fission. R5: AGPR accs. R6: MFMA layer-2, LDS Z (107.2us).
// R7-9: barrier-free k-split regressed. R10: swizzle/global A-frags regressed.
// R11: ez f32x4 neutral (107.1us) -> kernel is not issue-bound.
// R12: "transpose symmetry" elec_ji(i,j)=E[j][i] is WRONG: reference uses the
//   SAME e_ij for both orientations; e is asymmetric. absmax 0.25->0.875
//   (lucky pass). Also perf-neutral despite halved FLOPs + 7 blocks/CU ->
//   total is dominated by harness fill (43us @ 78% HBM) + restores, kernels
//   contribute only a few us. REVERTED to R11 (verified absmax 0.25).

#define NATOM 256
#define TOT_ATOMS 2048
#define ZS 40   // ushort elems per Z row: 80 B = 16B-aligned, 20-bank stride

typedef __bf16 bf16x8 __attribute__((ext_vector_type(8)));
typedef float  f32x16 __attribute__((ext_vector_type(16)));
typedef float  f32x4  __attribute__((ext_vector_type(4)));

__device__ __forceinline__ unsigned int pk2(float a, float b) {
    unsigned short lo = __builtin_bit_cast(unsigned short, (__bf16)a);
    unsigned short hi = __builtin_bit_cast(unsigned short, (__bf16)b);
    return (unsigned int)lo | ((unsigned int)hi << 16);
}

// ---- Kernel A: per-atom projections, P[atom][64]: c<32 = Pa, c>=32 = Pb+b1.
__global__ __launch_bounds__(256) void atom_proj_kernel(
    const float* __restrict__ x, const float* __restrict__ h,
    const float* __restrict__ q, const float* __restrict__ W1,
    const float* __restrict__ b1, float* __restrict__ P)
{
    const int a  = threadIdx.x >> 5;   // 0..7
    const int u  = threadIdx.x & 31;   // 0..31
    const int n0 = blockIdx.x * 8;

    __shared__ float sd[8][37];        // x(3), h(32), q(1), pad
    for (int idx = threadIdx.x; idx < 8 * 36; idx += 256) {
        const int aa = idx / 36, r = idx - aa * 36;
        const int n = n0 + aa;
        float v;
        if (r < 3)       v = x[n * 3 + r];
        else if (r < 35) v = h[n * 32 + (r - 3)];
        else             v = q[n];
        sd[aa][r] = v;
    }
    __syncthreads();

    float pa = 0.f, pb = b1[u];
#pragma unroll
    for (int r = 0; r < 36; ++r) {
        const float d = sd[a][r];
        pa += d * W1[r * 32 + u];
        pb += d * W1[(36 + r) * 32 + u];
    }
    const int n = n0 + a;
    P[(size_t)n * 64 + u]      = pa;
    P[(size_t)n * 64 + 32 + u] = pb;
}

// ---- Kernel B: one block per (b,i) row; VALU layer-1 (both orientations,
//      shared e_ij) -> bf16 Z in LDS -> MFMA layer-2 -> per-lane epilogue.
__global__ __launch_bounds__(256, 3) void pair_kernel(
    const float* __restrict__ e, const float* __restrict__ mask,
    const float* __restrict__ q, const float* __restrict__ P,
    const float* __restrict__ W1, const float* __restrict__ W2,
    const float* __restrict__ b2, const float* __restrict__ W3,
    float* __restrict__ out)
{
    const int row = blockIdx.x;          // b*256 + i == atom index of i
    const int b   = row >> 8;
    const int j   = threadIdx.x;
    const int col = (b << 8) + j;        // atom index of j

    __shared__ unsigned short Zij[256 * ZS];
    __shared__ unsigned short Zji[256 * ZS];
    __shared__ unsigned short W2t[32 * ZS];   // W2t[u][k] = W2[k][u], bf16
    __shared__ float g_lds[256];
    __shared__ float red[4];

    // ---- per-pair scalars
    const float* ep = e + (size_t)(row * NATOM + j) * 8;
    const float4 ev0 = ((const float4*)ep)[0];
    const float4 ev1 = ((const float4*)ep)[1];
    const float m = mask[row * NATOM + j];
    const float mx = fmaxf(fmaxf(fmaxf(ev0.x, ev0.y), fmaxf(ev0.z, ev0.w)),
                           fmaxf(fmaxf(ev1.x, ev1.y), fmaxf(ev1.z, ev1.w)));
    g_lds[j] = (mx > 1e-5f) ? 0.5f * m : 0.f;

    // ---- stage W2^T in bf16 (thread -> 4 entries)
    {
        const int u  = threadIdx.x >> 3;        // 0..31
        const int k0 = (threadIdx.x & 7) * 4;   // 0,4,..,28
        const unsigned int p0 = pk2(W2[(k0 + 0) * 32 + u], W2[(k0 + 1) * 32 + u]);
        const unsigned int p1 = pk2(W2[(k0 + 2) * 32 + u], W2[(k0 + 3) * 32 + u]);
        *(unsigned int*)&W2t[u * ZS + k0]     = p0;
        *(unsigned int*)&W2t[u * ZS + k0 + 2] = p1;
    }

    // ---- layer 1: z_ij/z_ji per k (shared e-projection), pack bf16 into LDS
    const float* Pi = P + (size_t)row * 64;   // uniform -> s_load
    const float* Pj = P + (size_t)col * 64;   // per-thread vector loads
#pragma unroll
    for (int kq = 0; kq < 8; ++kq) {
        const float4 paj4 = ((const float4*)Pj)[kq];
        const float4 pbj4 = ((const float4*)Pj)[8 + kq];
        const int k0 = kq * 4;

        // ez[0..3] for k = k0..k0+3, vectorized (W1 rows uniform -> s_load)
        f32x4 ez = {0.f, 0.f, 0.f, 0.f};
        ez += (*(const f32x4*)(W1 + (72 + 0) * 32 + k0)) * ev0.x;
        ez += (*(const f32x4*)(W1 + (72 + 1) * 32 + k0)) * ev0.y;
        ez += (*(const f32x4*)(W1 + (72 + 2) * 32 + k0)) * ev0.z;
        ez += (*(const f32x4*)(W1 + (72 + 3) * 32 + k0)) * ev0.w;
        ez += (*(const f32x4*)(W1 + (72 + 4) * 32 + k0)) * ev1.x;
        ez += (*(const f32x4*)(W1 + (72 + 5) * 32 + k0)) * ev1.y;
        ez += (*(const f32x4*)(W1 + (72 + 6) * 32 + k0)) * ev1.z;
        ez += (*(const f32x4*)(W1 + (72 + 7) * 32 + k0)) * ev1.w;

        const float zij0 = fmaxf(Pi[k0 + 0] + pbj4.x + ez[0], 0.f);
        const float zij1 = fmaxf(Pi[k0 + 1] + pbj4.y + ez[1], 0.f);
        const float zij2 = fmaxf(Pi[k0 + 2] + pbj4.z + ez[2], 0.f);
        const float zij3 = fmaxf(Pi[k0 + 3] + pbj4.w + ez[3], 0.f);
        const float zji0 = fmaxf(paj4.x + Pi[32 + k0 + 0] + ez[0], 0.f);
        const float zji1 = fmaxf(paj4.y + Pi[32 + k0 + 1] + ez[1], 0.f);
        const float zji2 = fmaxf(paj4.z + Pi[32 + k0 + 2] + ez[2], 0.f);
        const float zji3 = fmaxf(paj4.w + Pi[32 + k0 + 3] + ez[3], 0.f);

        *(uint2*)&Zij[j * ZS + k0] = make_uint2(pk2(zij0, zij1), pk2(zij2, zij3));
        *(uint2*)&Zji[j * ZS + k0] = make_uint2(pk2(zji0, zji1), pk2(zji2, zji3));
    }
    __syncthreads();

    // ---- layer 2 via MFMA: C[u][j'] = sum_k W2t[u][k] * Z[j'][k]
    const int wave = threadIdx.x >> 6;
    const int lane = threadIdx.x & 63;
    const int lo = lane & 31;     // = u for A, = j-col for B/C
    const int h  = lane >> 5;     // k-half selector / C row offset

    const bf16x8 a0 = *(const bf16x8*)&W2t[lo * ZS + h * 8];        // k 0..15
    const bf16x8 a1 = *(const bf16x8*)&W2t[lo * ZS + 16 + h * 8];   // k 16..31

    float vacc = 0.f;
#pragma unroll
    for (int nt = 0; nt < 2; ++nt) {
        const int jt = (wave + nt * 4) * 32;     // j-tile base
        const int zo = (jt + lo) * ZS + h * 8;
        f32x16 cij = {0.f}, cji = {0.f};
        {
            const bf16x8 bz0 = *(const bf16x8*)&Zij[zo];
            const bf16x8 bz1 = *(const bf16x8*)&Zij[zo + 16];
            cij = __builtin_amdgcn_mfma_f32_32x32x16_bf16(a0, bz0, cij, 0, 0, 0);
            cij = __builtin_amdgcn_mfma_f32_32x32x16_bf16(a1, bz1, cij, 0, 0, 0);
        }
        {
            const bf16x8 bz0 = *(const bf16x8*)&Zji[zo];
            const bf16x8 bz1 = *(const bf16x8*)&Zji[zo + 16];
            cji = __builtin_amdgcn_mfma_f32_32x32x16_bf16(a0, bz0, cji, 0, 0, 0);
            cji = __builtin_amdgcn_mfma_f32_32x32x16_bf16(a1, bz1, cji, 0, 0, 0);
        }
        // epilogue: per lane, 16 u-values (u = (reg&3)+8*(reg>>2)+4h), col j=jt+lo
        float d = 0.f;
#pragma unroll
        for (int reg = 0; reg < 16; ++reg) {
            const int u0 = (reg & 3) + 8 * (reg >> 2);
            const float b2v = h ? b2[u0 + 4] : b2[u0];
            const float w3v = h ? W3[u0 + 4] : W3[u0];
            const float rij = fmaxf(cij[reg] + b2v, 0.f);
            const float rji = fmaxf(cji[reg] + b2v, 0.f);
            d += (rij - rji) * w3v;
        }
        d += __shfl_xor(d, 32, 64);              // complete the 32-u sum
        vacc += d * g_lds[jt + lo];
    }

    // wave sum (each j counted in both halves -> x2), then block sum
#pragma unroll
    for (int off = 1; off < 64; off <<= 1)
        vacc += __shfl_xor(vacc, off, 64);
    if (lane == 0) red[wave] = vacc;
    __syncthreads();
    if (threadIdx.x == 0)
        out[row] = q[row] + 0.5f * (red[0] + red[1] + red[2] + red[3]);
}

extern "C" void kernel_launch(void* const* d_in, const int* in_sizes, int n_in,
                              void* d_out, int out_size, void* d_ws, size_t ws_size,
                              hipStream_t stream)
{
    const float* h    = (const float*)d_in[0];
    const float* e    = (const float*)d_in[1];
    const float* x    = (const float*)d_in[2];
    const float* q    = (const float*)d_in[3];
    const float* mask = (const float*)d_in[4];
    const float* W1   = (const float*)d_in[5];
    const float* b1   = (const float*)d_in[6];
    const float* W2   = (const float*)d_in[7];
    const float* b2   = (const float*)d_in[8];
    const float* W3   = (const float*)d_in[9];
    // b3 cancels in the antisymmetric difference.

    float* P = (float*)d_ws;  // [2048][64] floats = 512 KB

    atom_proj_kernel<<<256, 256, 0, stream>>>(x, h, q, W1, b1, P);
    pair_kernel<<<TOT_ATOMS, 256, 0, stream>>>(e, mask, q, P, W1, W2, b2, W3,
                                               (float*)d_out);
}